// Round 3
// baseline (9696.725 us; speedup 1.0000x reference)
//
#include <hip/hip_runtime.h>
#include <hip/hip_cooperative_groups.h>

namespace cg = cooperative_groups;

// CNN_RNN: 8×(257,2176) → 256 windows (256×128) → conv9x9/16 +lrelu +pool3
//          → conv4x4 16→16 +lrelu +pool3 → (32,8,6272) → GRU(3136) ×32 → FC(2)
// R3: (A) persistent cooperative GRU — w_hh held in VGPRs as bf16 MFMA frags,
//     loaded once from fp32, 32 steps with grid.sync (replaces 32 launches +
//     cvt kernel). (B) conv1: unroll-1 task loop + launch_bounds(256,4) to fix
//     the 256-VGPR / 11.8%-occupancy blowup seen in R2 counters.

typedef unsigned short u16;
using bf16x8 = __attribute__((ext_vector_type(8))) short;
using f32x4  = __attribute__((ext_vector_type(4))) float;
#define MFMA16(a,b,c) __builtin_amdgcn_mfma_f32_16x16x32_bf16(a,b,c,0,0,0)

__device__ __forceinline__ u16 f2b(float f){
  union { float f; unsigned u; } v; v.f = f;
  unsigned r = v.u + 0x7fffu + ((v.u >> 16) & 1u);
  return (u16)(r >> 16);
}
__device__ __forceinline__ float b2f(u16 h){
  union { unsigned u; float f; } v; v.u = ((unsigned)h) << 16; return v.f;
}
__device__ __forceinline__ f32x4 zero4(){ f32x4 v; v[0]=0.f; v[1]=0.f; v[2]=0.f; v[3]=0.f; return v; }

// ---------------- K0b: init h buffers ---------------------------------------
// hb buffers are [16][3136] bf16 (rows 8..15 zero pad for MFMA M=16).
__global__ __launch_bounds__(256) void k_init_h(const float* __restrict__ h0,
                u16* __restrict__ hb0, u16* __restrict__ hb1, float* __restrict__ hf0){
  int t = blockIdx.x*256 + threadIdx.x;
  if (t >= 16*3136) return;
  int row = t / 3136;
  u16 v = 0;
  if (row < 8){ float f = h0[t]; v = f2b(f); hf0[t] = f; }
  hb0[t] = v;
  hb1[t] = 0;
}

// ---------------- K2a: prepack conv2 weights into MFMA B-frag order ---------
__global__ __launch_bounds__(256) void k_pack_w2(const float* __restrict__ w2,
                                                 u16* __restrict__ w2pk){
  int t = blockIdx.x*256 + threadIdx.x;
  if (t >= 4096) return;
  int j = t & 7, co = (t>>3) & 15, g = (t>>7) & 3, m = t >> 9;
  int tap = 2*m + (g>>1);
  int ci = (g&1)*8 + j;
  int kh = tap >> 2, kw = tap & 3;
  w2pk[t] = f2b(w2[((co*16 + ci)*4 + kh)*4 + kw]);
}

// ---------------- K1: conv1(9x9,pad2)+bias+lrelu+maxpool3x3 (fp32) ----------
// R3 fix: #pragma unroll 1 on the task loop (R2: full unroll -> 256 VGPR,
// 11.8% occupancy). launch_bounds(256,4) caps VGPR at 128 -> 4 blocks/CU.
__global__ __launch_bounds__(256, 4) void k_conv1(const float* __restrict__ x,
        const float* __restrict__ w1, const float* __restrict__ b1,
        u16* __restrict__ y1){
  __shared__ float in_s[20][134];
  __shared__ float w_s[16][81];
  __shared__ float bias_s[16];
  int pht = blockIdx.x;          // 0..20
  int img = blockIdx.y;          // b*32+k
  int b = img >> 5, k = img & 31;
  int oh0 = pht * 12;            // conv rows oh0..oh0+11
  const float* xb = x + ((size_t)b*257 + 1)*2176 + k*64;  // xb[f*2176 + t]
  for (int p = threadIdx.x; p < 20*134; p += 256){
    int rr = p / 134, cc = p % 134;
    int f = oh0 - 2 + rr, t = cc - 2;
    float v = 0.f;
    if (f >= 0 && f < 256 && t >= 0 && t < 128) v = xb[(size_t)f*2176 + t];
    in_s[rr][cc] = v;
  }
  for (int p = threadIdx.x; p < 16*81; p += 256) w_s[p/81][p%81] = w1[p];
  if (threadIdx.x < 16) bias_s[threadIdx.x] = b1[threadIdx.x];
  __syncthreads();
  int c = threadIdx.x >> 4, sub = threadIdx.x & 15;
  float bias = bias_s[c];
#pragma unroll 1
  for (int i = 0; i < 6; ++i){
    int idx = sub + 16*i;                 // (ph_l, strip) tasks: 4*21 = 84
    if (idx >= 84) break;
    int ph_l = idx / 21;
    int s    = idx % 21;
    float acc[3][6];
#pragma unroll
    for (int dh=0; dh<3; ++dh)
#pragma unroll
      for (int q=0; q<6; ++q) acc[dh][q] = bias;
#pragma unroll
    for (int ir = 0; ir < 11; ++ir){
      int rr = ph_l*3 + ir;
      float v[14];
#pragma unroll
      for (int q=0; q<14; ++q) v[q] = in_s[rr][s*6 + q];
#pragma unroll
      for (int dh=0; dh<3; ++dh){
        int kh = ir - dh;
        if (kh >= 0 && kh < 9){
#pragma unroll
          for (int kw=0; kw<9; ++kw){
            float w = w_s[c][kh*9 + kw];
#pragma unroll
            for (int q=0; q<6; ++q) acc[dh][q] += w * v[q + kw];
          }
        }
      }
    }
    float p0 = -1e30f, p1 = -1e30f;
#pragma unroll
    for (int dh=0; dh<3; ++dh)
#pragma unroll
      for (int q=0; q<3; ++q){
        float a0 = acc[dh][q];   a0 = a0 > 0.f ? a0 : 0.01f*a0;
        float a1 = acc[dh][q+3]; a1 = a1 > 0.f ? a1 : 0.01f*a1;
        p0 = fmaxf(p0, a0); p1 = fmaxf(p1, a1);
      }
    int ph = pht*4 + ph_l;
    int pw = 2*s;
    size_t base = ((size_t)img*84 + ph)*41;
    y1[(base + pw)*16 + c] = f2b(p0);
    if (pw + 1 < 41) y1[(base + pw + 1)*16 + c] = f2b(p1);
  }
}

// ---------------- K2: conv2(4x4,pad2)+bias+lrelu+maxpool3x3 via MFMA --------
__global__ __launch_bounds__(256) void k_conv2(const u16* __restrict__ y1,
        const u16* __restrict__ w2pk, const float* __restrict__ b2,
        u16* __restrict__ yb){
  __shared__ u16 stage[15][52][16];
  __shared__ u16 conv_s[12][48][16];
  int img = blockIdx.y, pht = blockIdx.x;
  int oh0 = pht*12;
  for (int p = threadIdx.x; p < 15*52; p += 256){
    int rr = p / 52, cc = p % 52;
    int ih = oh0 - 2 + rr, iw = cc - 2;
    uint4 a = make_uint4(0,0,0,0), bb = a;
    if (ih >= 0 && ih < 84 && iw >= 0 && iw < 41){
      const uint4* src = (const uint4*)(y1 + (((size_t)img*84 + ih)*41 + iw)*16);
      a = src[0]; bb = src[1];
    }
    *((uint4*)&stage[rr][cc][0]) = a;
    *((uint4*)&stage[rr][cc][8]) = bb;
  }
  int lane = threadIdx.x & 63, wv = threadIdx.x >> 6;
  bf16x8 bfr[8];
#pragma unroll
  for (int m = 0; m < 8; ++m)
    bfr[m] = *(const bf16x8*)(w2pk + ((m*4 + (lane>>4))*16 + (lane&15))*8);
  float bias = b2[lane & 15];
  __syncthreads();
  int g = lane >> 4;
  for (int task = wv; task < 12; task += 4){
    int owt = task % 3, phh = task / 3;
    int ow0 = owt*16;
#pragma unroll
    for (int dh = 0; dh < 3; ++dh){
      int oh_l = phh*3 + dh;
      f32x4 acc = zero4();
#pragma unroll
      for (int m = 0; m < 8; ++m){
        int tap = 2*m + (g>>1);
        int kh = tap >> 2, kw = tap & 3;
        int iw = ow0 + (lane&15) - 2 + kw;
        const u16* ap = &stage[oh_l + kh][iw + 2][(g&1)*8];
        bf16x8 af = *(const bf16x8*)ap;
        acc = MFMA16(af, bfr[m], acc);
      }
#pragma unroll
      for (int j = 0; j < 4; ++j){
        float v = acc[j] + bias;
        v = v > 0.f ? v : 0.01f*v;
        int ow = ow0 + (lane>>4)*4 + j;
        conv_s[oh_l][ow][lane&15] = f2b(v);
      }
    }
  }
  __syncthreads();
  int img_b = img >> 5, img_k = img & 31;
  for (int p = threadIdx.x; p < 896; p += 256){
    int co = p & 15; int rem = p >> 4; int pw = rem % 14; int phh = rem / 14;
    float mx = -1e30f;
#pragma unroll
    for (int dh=0; dh<3; ++dh)
#pragma unroll
      for (int dw=0; dw<3; ++dw)
        mx = fmaxf(mx, b2f(conv_s[phh*3+dh][pw*3+dw][co]));
    int ph = pht*4 + phh;
    int i = co*392 + ph*14 + pw;
    yb[((size_t)img_k*8 + img_b)*6272 + i] = f2b(mx);
  }
}

// ---------------- K3: gi = Y @ w_ih^T + b_ih (all 32 steps at once) ---------
__global__ __launch_bounds__(256) void k_gemm_gi(const u16* __restrict__ yb,
        const float* __restrict__ w_ih, const float* __restrict__ b_ih,
        float* __restrict__ gi){
  int lane = threadIdx.x & 63, wv = threadIdx.x >> 6;
  int n0 = blockIdx.x*64 + wv*16;
  int ra = lane & 15, ga = lane >> 4;
  f32x4 acc[16];
#pragma unroll
  for (int m=0; m<16; ++m) acc[m] = zero4();
  const float* wrow = w_ih + (size_t)(n0 + ra)*6272 + ga*8;
  for (int k0 = 0; k0 < 6272; k0 += 32){
    float4 lo = *(const float4*)(wrow + k0);
    float4 hi = *(const float4*)(wrow + k0 + 4);
    bf16x8 bf;
    bf[0]=(short)f2b(lo.x); bf[1]=(short)f2b(lo.y); bf[2]=(short)f2b(lo.z); bf[3]=(short)f2b(lo.w);
    bf[4]=(short)f2b(hi.x); bf[5]=(short)f2b(hi.y); bf[6]=(short)f2b(hi.z); bf[7]=(short)f2b(hi.w);
#pragma unroll
    for (int m=0; m<16; ++m){
      bf16x8 af = *(const bf16x8*)(yb + (size_t)(m*16 + ra)*6272 + k0 + ga*8);
      acc[m] = MFMA16(af, bf, acc[m]);
    }
  }
  float bias = b_ih[n0 + ra];
  int col = n0 + ra;
#pragma unroll
  for (int m=0; m<16; ++m)
#pragma unroll
    for (int j=0; j<4; ++j){
      int r = m*16 + (lane>>4)*4 + j;
      gi[(size_t)r*9408 + col] = acc[m][j] + bias;
    }
}

// ---------------- K4: ALL 32 GRU steps, persistent cooperative --------------
// 196 blocks (=16 hidden cols each) × 512 thr (8 waves). Each wave holds
// 3 gates × 13 k-chunks of w_hh as bf16 MFMA B-frags in VGPRs (156 VGPR),
// loaded ONCE from fp32 w_hh. Per step: 13×(1 A-load + 3 MFMA) + LDS reduce
// + fused gate epilogue + grid.sync(). h carry fp32 + bf16 ping-pong in ws.
__global__ __launch_bounds__(512, 2) void k_gru_all(
        const float* __restrict__ whh, const float* __restrict__ gi,
        const float* __restrict__ b_hh,
        u16* __restrict__ hb0, u16* __restrict__ hb1,
        float* __restrict__ hf0, float* __restrict__ hf1){
  cg::grid_group grid = cg::this_grid();
  __shared__ float red[8][3][16][16];
  int lane = threadIdx.x & 63, wv = threadIdx.x >> 6;
  int ra = lane & 15, ga = lane >> 4;
  int jb = blockIdx.x * 16;

  // one-time: load 39 B-frags from fp32 w_hh (row = g*3136 + jb + ra)
  bf16x8 bfr[3][13];
#pragma unroll
  for (int g = 0; g < 3; ++g){
    const float* wbase = whh + ((size_t)(g*3136 + jb + ra))*3136 + ga*8;
#pragma unroll
    for (int i = 0; i < 13; ++i){
      int kk = wv*13 + i;
      bf16x8 f;
      if (kk < 98){
        float4 lo = *(const float4*)(wbase + (size_t)kk*32);
        float4 hi = *(const float4*)(wbase + (size_t)kk*32 + 4);
        f[0]=(short)f2b(lo.x); f[1]=(short)f2b(lo.y); f[2]=(short)f2b(lo.z); f[3]=(short)f2b(lo.w);
        f[4]=(short)f2b(hi.x); f[5]=(short)f2b(hi.y); f[6]=(short)f2b(hi.z); f[7]=(short)f2b(hi.w);
      } else {
        f[0]=0;f[1]=0;f[2]=0;f[3]=0;f[4]=0;f[5]=0;f[6]=0;f[7]=0;
      }
      bfr[g][i] = f;
    }
  }

  for (int t = 0; t < 32; ++t){
    const u16*   hbi = (t & 1) ? hb1 : hb0;
    const float* hfi = (t & 1) ? hf1 : hf0;
    u16*         hbo = (t & 1) ? hb0 : hb1;
    float*       hfo = (t & 1) ? hf0 : hf1;
    const float* gi_t = gi + (size_t)t*8*9408;

    grid.sync();   // prev step's h writes visible; also guards red[] reuse

    f32x4 a0 = zero4(), a1 = zero4(), a2 = zero4();
    const u16* arow = hbi + (size_t)ra*3136 + ga*8;
#pragma unroll
    for (int i = 0; i < 13; ++i){
      int kk = wv*13 + i;
      if (kk < 98){
        bf16x8 af = *(const bf16x8*)(arow + kk*32);
        a0 = MFMA16(af, bfr[0][i], a0);
        a1 = MFMA16(af, bfr[1][i], a1);
        a2 = MFMA16(af, bfr[2][i], a2);
      }
    }
#pragma unroll
    for (int j=0; j<4; ++j){
      int row = ga*4 + j;           // batch (M)
      red[wv][0][row][ra] = a0[j];
      red[wv][1][row][ra] = a1[j];
      red[wv][2][row][ra] = a2[j];
    }
    __syncthreads();
    if (threadIdx.x < 128){
      int b = threadIdx.x & 7, jl = threadIdx.x >> 3;
      int j = jb + jl;
      float gh[3];
#pragma unroll
      for (int g3=0; g3<3; ++g3){
        float s = 0.f;
#pragma unroll
        for (int w=0; w<8; ++w) s += red[w][g3][b][jl];
        gh[g3] = s + b_hh[g3*3136 + j];
      }
      float gir = gi_t[(size_t)b*9408 + j];
      float giz = gi_t[(size_t)b*9408 + 3136 + j];
      float gin = gi_t[(size_t)b*9408 + 6272 + j];
      float r = 1.f/(1.f + expf(-(gir + gh[0])));
      float z = 1.f/(1.f + expf(-(giz + gh[1])));
      float n = tanhf(gin + r*gh[2]);
      float h = (1.f - z)*n + z*hfi[b*3136 + j];
      hfo[b*3136 + j] = h;
      hbo[b*3136 + j] = f2b(h);
    }
  }
}

// ---------------- K5: out = h @ fc_w^T + fc_b -------------------------------
__global__ __launch_bounds__(64) void k_fc(const float* __restrict__ hf,
        const float* __restrict__ fc_w, const float* __restrict__ fc_b,
        float* __restrict__ out){
  int b = blockIdx.x >> 1, o = blockIdx.x & 1;
  int lane = threadIdx.x;
  float s = 0.f;
  for (int i = lane; i < 3136; i += 64) s += hf[b*3136 + i] * fc_w[o*3136 + i];
#pragma unroll
  for (int off = 32; off; off >>= 1) s += __shfl_down(s, off);
  if (lane == 0) out[b*2 + o] = s + fc_b[o];
}

extern "C" void kernel_launch(void* const* d_in, const int* in_sizes, int n_in,
                              void* d_out, int out_size, void* d_ws, size_t ws_size,
                              hipStream_t stream) {
  const float* x   = (const float*)d_in[0];
  const float* h0  = (const float*)d_in[1];
  const float* w1  = (const float*)d_in[2];
  const float* b1  = (const float*)d_in[3];
  const float* w2  = (const float*)d_in[4];
  const float* b2  = (const float*)d_in[5];
  const float* wih = (const float*)d_in[6];
  const float* whh = (const float*)d_in[7];
  const float* bih = (const float*)d_in[8];
  const float* bhh = (const float*)d_in[9];
  const float* fcw = (const float*)d_in[10];
  const float* fcb = (const float*)d_in[11];

  char* p = (char*)d_ws;
  u16*   y1    = (u16*)p;   p += 28213248ull;   // 256*84*41*16 bf16 (NHWC)
  u16*   yb    = (u16*)p;   p += 3211264ull;    // 32*8*6272 bf16
  float* gi    = (float*)p; p += 9633792ull;    // 256*9408 f32
  u16*   w2pk  = (u16*)p;   p += 8192ull;       // packed conv2 weights
  float* hf0   = (float*)p; p += 100352ull;     // 8*3136 f32
  float* hf1   = (float*)p; p += 100352ull;
  u16*   hb0   = (u16*)p;   p += 100352ull;     // 16*3136 bf16 (padded)
  u16*   hb1   = (u16*)p;   p += 100352ull;
  // total ≈ 41.5 MB

  k_init_h<<<196, 256, 0, stream>>>(h0, hb0, hb1, hf0);
  k_pack_w2<<<16, 256, 0, stream>>>(w2, w2pk);
  k_conv1<<<dim3(21, 256), 256, 0, stream>>>(x, w1, b1, y1);
  k_conv2<<<dim3(7, 256), 256, 0, stream>>>(y1, w2pk, b2, yb);
  k_gemm_gi<<<147, 256, 0, stream>>>(yb, wih, bih, gi);

  void* args[] = { (void*)&whh, (void*)&gi, (void*)&bhh,
                   (void*)&hb0, (void*)&hb1, (void*)&hf0, (void*)&hf1 };
  hipLaunchCooperativeKernel((void*)k_gru_all, dim3(196), dim3(512),
                             args, 0, stream);

  k_fc<<<16, 64, 0, stream>>>(hf0, fcw, fcb, (float*)d_out);
}

// Round 4
// 1810.699 us; speedup vs baseline: 5.3552x; 5.3552x over previous
//
#include <hip/hip_runtime.h>
#include <hip/hip_cooperative_groups.h>

namespace cg = cooperative_groups;

// CNN_RNN: 8×(257,2176) → 256 windows (256×128) → conv9x9/16 +lrelu +pool3
//          → conv4x4 16→16 +lrelu +pool3 → (32,8,6272) → GRU(3136) ×32 → FC(2)
// R4: (A) conv1 rewritten as MFMA: taps packed as 5 K=32 steps (kh-pairs × 16
//     kw-slots, zero-padded in weights), A-frags from a 2-copy parity-shifted
//     LDS image (4B-aligned dword reads regardless of start-col parity).
//     R3's spill disaster (64-VGPR cap -> 28.9 GB scratch traffic) is gone.
// (B) k_gru_all launch_bounds(512,1): bfr[3][13]=156 VGPR must NOT be capped
//     at 128 (R3 spilled). ~220 VGPR fits 8-wave blocks (<=256).

typedef unsigned short u16;
typedef unsigned int u32;
using bf16x8 = __attribute__((ext_vector_type(8))) short;
using f32x4  = __attribute__((ext_vector_type(4))) float;
#define MFMA16(a,b,c) __builtin_amdgcn_mfma_f32_16x16x32_bf16(a,b,c,0,0,0)

__device__ __forceinline__ u16 f2b(float f){
  union { float f; unsigned u; } v; v.f = f;
  unsigned r = v.u + 0x7fffu + ((v.u >> 16) & 1u);
  return (u16)(r >> 16);
}
__device__ __forceinline__ float b2f(u16 h){
  union { unsigned u; float f; } v; v.u = ((unsigned)h) << 16; return v.f;
}
__device__ __forceinline__ f32x4 zero4(){ f32x4 v; v[0]=0.f; v[1]=0.f; v[2]=0.f; v[3]=0.f; return v; }

// ---------------- K0b: init h buffers ---------------------------------------
__global__ __launch_bounds__(256) void k_init_h(const float* __restrict__ h0,
                u16* __restrict__ hb0, u16* __restrict__ hb1, float* __restrict__ hf0){
  int t = blockIdx.x*256 + threadIdx.x;
  if (t >= 16*3136) return;
  int row = t / 3136;
  u16 v = 0;
  if (row < 8){ float f = h0[t]; v = f2b(f); hf0[t] = f; }
  hb0[t] = v;
  hb1[t] = 0;
}

// ---------------- prepack conv1 weights into 5 MFMA B-frags -----------------
// w1pk[(mm*64+lane)*8+j]: ch=lane&15, ga=lane>>4, kh=2mm+(ga>>1), kw=(ga&1)*8+j
// zero outside kh<9, kw<9 (weight-side padding makes junk A-cols harmless).
__global__ __launch_bounds__(256) void k_pack_w1(const float* __restrict__ w1,
                                                 u16* __restrict__ w1pk){
  int t = blockIdx.x*256 + threadIdx.x;
  if (t >= 2560) return;
  int j = t & 7, lane = (t>>3) & 63, mm = t >> 9;
  int ra = lane & 15, ga = lane >> 4;
  int kh = 2*mm + (ga>>1), kw = (ga&1)*8 + j;
  float v = (kh < 9 && kw < 9) ? w1[ra*81 + kh*9 + kw] : 0.f;
  w1pk[t] = f2b(v);
}

// ---------------- prepack conv2 weights into MFMA B-frag order --------------
__global__ __launch_bounds__(256) void k_pack_w2(const float* __restrict__ w2,
                                                 u16* __restrict__ w2pk){
  int t = blockIdx.x*256 + threadIdx.x;
  if (t >= 4096) return;
  int j = t & 7, co = (t>>3) & 15, g = (t>>7) & 3, m = t >> 9;
  int tap = 2*m + (g>>1);
  int ci = (g&1)*8 + j;
  int kh = tap >> 2, kw = tap & 3;
  w2pk[t] = f2b(w2[((co*16 + ci)*4 + kh)*4 + kw]);
}

// ---------------- K1: conv1 via MFMA + pool ---------------------------------
// Block (pht 0..20, img): 12 conv rows (oh0..oh0+11), all 123 cols as 8 tiles
// of 16 pixels. x staged in LDS as TWO parity-shifted bf16 copies:
//   xc[0][r][i] = x(col i-2), xc[1][r][i] = x(col i-1)
// so a lane needing 8 bf16 from col s reads 4 dwords at dword ((s+2)-par)/2 of
// copy par, par = (s+2)&1 — always 4B aligned.
__global__ __launch_bounds__(256, 2) void k_conv1(const float* __restrict__ x,
        const u16* __restrict__ w1pk, const float* __restrict__ b1,
        u16* __restrict__ y1){
  __shared__ u16 xc[2][20][144];        // 11.5 KB
  __shared__ u16 conv_s[12][16][132];   // 50.7 KB, ch-major, +4 col pad
  int pht = blockIdx.x;
  int img = blockIdx.y;
  int b = img >> 5, k = img & 31;
  int oh0 = pht * 12;
  const float* xb = x + ((size_t)b*257 + 1)*2176 + (size_t)k*64;
  for (int p = threadIdx.x; p < 2*20*144; p += 256){
    int cp = p / (20*144); int rem = p % (20*144);
    int r = rem / 144, i = rem % 144;
    int c = i - 2 + cp;                 // copy0: col=i-2, copy1: col=i-1
    int f = oh0 - 2 + r;
    float v = 0.f;
    if (f >= 0 && f < 256 && c >= 0 && c < 128) v = xb[(size_t)f*2176 + c];
    xc[cp][r][i] = f2b(v);
  }
  int lane = threadIdx.x & 63, wv = threadIdx.x >> 6;
  int ra = lane & 15, ga = lane >> 4;
  bf16x8 wf[5];
#pragma unroll
  for (int mm = 0; mm < 5; ++mm)
    wf[mm] = *(const bf16x8*)(w1pk + ((size_t)(mm*64 + lane))*8);
  float bias = b1[ra];
  __syncthreads();
  const u32* xc0 = (const u32*)&xc[0][0][0];
  // 96 (row,tile) tasks over 4 waves
  for (int task = wv; task < 96; task += 4){
    int row = task >> 3, tile = task & 7, c0 = tile*16;
    int i0 = c0 + ra + (ga&1)*8;        // = start_col + 2
    int par = i0 & 1;
    int dwbase = par*1440 + ((i0 - par) >> 1);   // copy stride 20*144/2 dwords
    f32x4 acc = zero4();
#pragma unroll
    for (int mm = 0; mm < 5; ++mm){
      int r_in = row + 2*mm + (ga>>1);
      if (r_in > 19) r_in = 19;         // kh>=9 lanes: weight is zero anyway
      const u32* pp = xc0 + dwbase + r_in*72;
      union { u32 u[4]; bf16x8 v; } cv;
      cv.u[0] = pp[0]; cv.u[1] = pp[1]; cv.u[2] = pp[2]; cv.u[3] = pp[3];
      acc = MFMA16(cv.v, wf[mm], acc);
    }
#pragma unroll
    for (int j = 0; j < 4; ++j){
      float v = acc[j] + bias;
      v = v > 0.f ? v : 0.01f*v;
      conv_s[row][ra][c0 + ga*4 + j] = f2b(v);  // D: ch=lane&15, px=(lane>>4)*4+j
    }
  }
  __syncthreads();
  // pool 3x3: 4 pooled rows × 41 cols × 16 ch = 2624 outputs
  for (int p = threadIdx.x; p < 2624; p += 256){
    int co = p & 15; int q = p >> 4; int pw = q % 41; int ph_l = q / 41;
    float mx = -1e30f;
#pragma unroll
    for (int dh = 0; dh < 3; ++dh)
#pragma unroll
      for (int dw = 0; dw < 3; ++dw)
        mx = fmaxf(mx, b2f(conv_s[ph_l*3 + dh][co][pw*3 + dw]));
    y1[(((size_t)img*84 + pht*4 + ph_l)*41 + pw)*16 + co] = f2b(mx);
  }
}

// ---------------- K2: conv2(4x4,pad2)+bias+lrelu+maxpool3x3 via MFMA --------
__global__ __launch_bounds__(256) void k_conv2(const u16* __restrict__ y1,
        const u16* __restrict__ w2pk, const float* __restrict__ b2,
        u16* __restrict__ yb){
  __shared__ u16 stage[15][52][16];
  __shared__ u16 conv_s[12][48][16];
  int img = blockIdx.y, pht = blockIdx.x;
  int oh0 = pht*12;
  for (int p = threadIdx.x; p < 15*52; p += 256){
    int rr = p / 52, cc = p % 52;
    int ih = oh0 - 2 + rr, iw = cc - 2;
    uint4 a = make_uint4(0,0,0,0), bb = a;
    if (ih >= 0 && ih < 84 && iw >= 0 && iw < 41){
      const uint4* src = (const uint4*)(y1 + (((size_t)img*84 + ih)*41 + iw)*16);
      a = src[0]; bb = src[1];
    }
    *((uint4*)&stage[rr][cc][0]) = a;
    *((uint4*)&stage[rr][cc][8]) = bb;
  }
  int lane = threadIdx.x & 63, wv = threadIdx.x >> 6;
  bf16x8 bfr[8];
#pragma unroll
  for (int m = 0; m < 8; ++m)
    bfr[m] = *(const bf16x8*)(w2pk + ((m*4 + (lane>>4))*16 + (lane&15))*8);
  float bias = b2[lane & 15];
  __syncthreads();
  int g = lane >> 4;
  for (int task = wv; task < 12; task += 4){
    int owt = task % 3, phh = task / 3;
    int ow0 = owt*16;
#pragma unroll
    for (int dh = 0; dh < 3; ++dh){
      int oh_l = phh*3 + dh;
      f32x4 acc = zero4();
#pragma unroll
      for (int m = 0; m < 8; ++m){
        int tap = 2*m + (g>>1);
        int kh = tap >> 2, kw = tap & 3;
        int iw = ow0 + (lane&15) - 2 + kw;
        const u16* ap = &stage[oh_l + kh][iw + 2][(g&1)*8];
        bf16x8 af = *(const bf16x8*)ap;
        acc = MFMA16(af, bfr[m], acc);
      }
#pragma unroll
      for (int j = 0; j < 4; ++j){
        float v = acc[j] + bias;
        v = v > 0.f ? v : 0.01f*v;
        int ow = ow0 + (lane>>4)*4 + j;
        conv_s[oh_l][ow][lane&15] = f2b(v);
      }
    }
  }
  __syncthreads();
  int img_b = img >> 5, img_k = img & 31;
  for (int p = threadIdx.x; p < 896; p += 256){
    int co = p & 15; int rem = p >> 4; int pw = rem % 14; int phh = rem / 14;
    float mx = -1e30f;
#pragma unroll
    for (int dh=0; dh<3; ++dh)
#pragma unroll
      for (int dw=0; dw<3; ++dw)
        mx = fmaxf(mx, b2f(conv_s[phh*3+dh][pw*3+dw][co]));
    int ph = pht*4 + phh;
    int i = co*392 + ph*14 + pw;
    yb[((size_t)img_k*8 + img_b)*6272 + i] = f2b(mx);
  }
}

// ---------------- K3: gi = Y @ w_ih^T + b_ih (all 32 steps at once) ---------
__global__ __launch_bounds__(256) void k_gemm_gi(const u16* __restrict__ yb,
        const float* __restrict__ w_ih, const float* __restrict__ b_ih,
        float* __restrict__ gi){
  int lane = threadIdx.x & 63, wv = threadIdx.x >> 6;
  int n0 = blockIdx.x*64 + wv*16;
  int ra = lane & 15, ga = lane >> 4;
  f32x4 acc[16];
#pragma unroll
  for (int m=0; m<16; ++m) acc[m] = zero4();
  const float* wrow = w_ih + (size_t)(n0 + ra)*6272 + ga*8;
  for (int k0 = 0; k0 < 6272; k0 += 32){
    float4 lo = *(const float4*)(wrow + k0);
    float4 hi = *(const float4*)(wrow + k0 + 4);
    bf16x8 bf;
    bf[0]=(short)f2b(lo.x); bf[1]=(short)f2b(lo.y); bf[2]=(short)f2b(lo.z); bf[3]=(short)f2b(lo.w);
    bf[4]=(short)f2b(hi.x); bf[5]=(short)f2b(hi.y); bf[6]=(short)f2b(hi.z); bf[7]=(short)f2b(hi.w);
#pragma unroll
    for (int m=0; m<16; ++m){
      bf16x8 af = *(const bf16x8*)(yb + (size_t)(m*16 + ra)*6272 + k0 + ga*8);
      acc[m] = MFMA16(af, bf, acc[m]);
    }
  }
  float bias = b_ih[n0 + ra];
  int col = n0 + ra;
#pragma unroll
  for (int m=0; m<16; ++m)
#pragma unroll
    for (int j=0; j<4; ++j){
      int r = m*16 + (lane>>4)*4 + j;
      gi[(size_t)r*9408 + col] = acc[m][j] + bias;
    }
}

// ---------------- K4: ALL 32 GRU steps, persistent cooperative --------------
// launch_bounds(512,1): bfr needs 156 VGPR; R3's (512,2)=128-cap spilled to
// scratch. ~220 VGPR fits (8-wave block residency needs <=256).
__global__ __launch_bounds__(512, 1) void k_gru_all(
        const float* __restrict__ whh, const float* __restrict__ gi,
        const float* __restrict__ b_hh,
        u16* __restrict__ hb0, u16* __restrict__ hb1,
        float* __restrict__ hf0, float* __restrict__ hf1){
  cg::grid_group grid = cg::this_grid();
  __shared__ float red[8][3][16][16];
  int lane = threadIdx.x & 63, wv = threadIdx.x >> 6;
  int ra = lane & 15, ga = lane >> 4;
  int jb = blockIdx.x * 16;

  bf16x8 bfr[3][13];
#pragma unroll
  for (int g = 0; g < 3; ++g){
    const float* wbase = whh + ((size_t)(g*3136 + jb + ra))*3136 + ga*8;
#pragma unroll
    for (int i = 0; i < 13; ++i){
      int kk = wv*13 + i;
      bf16x8 f;
      if (kk < 98){
        float4 lo = *(const float4*)(wbase + (size_t)kk*32);
        float4 hi = *(const float4*)(wbase + (size_t)kk*32 + 4);
        f[0]=(short)f2b(lo.x); f[1]=(short)f2b(lo.y); f[2]=(short)f2b(lo.z); f[3]=(short)f2b(lo.w);
        f[4]=(short)f2b(hi.x); f[5]=(short)f2b(hi.y); f[6]=(short)f2b(hi.z); f[7]=(short)f2b(hi.w);
      } else {
        f[0]=0;f[1]=0;f[2]=0;f[3]=0;f[4]=0;f[5]=0;f[6]=0;f[7]=0;
      }
      bfr[g][i] = f;
    }
  }

  for (int t = 0; t < 32; ++t){
    const u16*   hbi = (t & 1) ? hb1 : hb0;
    const float* hfi = (t & 1) ? hf1 : hf0;
    u16*         hbo = (t & 1) ? hb0 : hb1;
    float*       hfo = (t & 1) ? hf0 : hf1;
    const float* gi_t = gi + (size_t)t*8*9408;

    grid.sync();

    f32x4 a0 = zero4(), a1 = zero4(), a2 = zero4();
    const u16* arow = hbi + (size_t)ra*3136 + ga*8;
#pragma unroll
    for (int i = 0; i < 13; ++i){
      int kk = wv*13 + i;
      if (kk < 98){
        bf16x8 af = *(const bf16x8*)(arow + kk*32);
        a0 = MFMA16(af, bfr[0][i], a0);
        a1 = MFMA16(af, bfr[1][i], a1);
        a2 = MFMA16(af, bfr[2][i], a2);
      }
    }
#pragma unroll
    for (int j=0; j<4; ++j){
      int row = ga*4 + j;
      red[wv][0][row][ra] = a0[j];
      red[wv][1][row][ra] = a1[j];
      red[wv][2][row][ra] = a2[j];
    }
    __syncthreads();
    if (threadIdx.x < 128){
      int b = threadIdx.x & 7, jl = threadIdx.x >> 3;
      int j = jb + jl;
      float gh[3];
#pragma unroll
      for (int g3=0; g3<3; ++g3){
        float s = 0.f;
#pragma unroll
        for (int w=0; w<8; ++w) s += red[w][g3][b][jl];
        gh[g3] = s + b_hh[g3*3136 + j];
      }
      float gir = gi_t[(size_t)b*9408 + j];
      float giz = gi_t[(size_t)b*9408 + 3136 + j];
      float gin = gi_t[(size_t)b*9408 + 6272 + j];
      float r = 1.f/(1.f + expf(-(gir + gh[0])));
      float z = 1.f/(1.f + expf(-(giz + gh[1])));
      float n = tanhf(gin + r*gh[2]);
      float h = (1.f - z)*n + z*hfi[b*3136 + j];
      hfo[b*3136 + j] = h;
      hbo[b*3136 + j] = f2b(h);
    }
  }
}

// ---------------- K5: out = h @ fc_w^T + fc_b -------------------------------
__global__ __launch_bounds__(64) void k_fc(const float* __restrict__ hf,
        const float* __restrict__ fc_w, const float* __restrict__ fc_b,
        float* __restrict__ out){
  int b = blockIdx.x >> 1, o = blockIdx.x & 1;
  int lane = threadIdx.x;
  float s = 0.f;
  for (int i = lane; i < 3136; i += 64) s += hf[b*3136 + i] * fc_w[o*3136 + i];
#pragma unroll
  for (int off = 32; off; off >>= 1) s += __shfl_down(s, off);
  if (lane == 0) out[b*2 + o] = s + fc_b[o];
}

extern "C" void kernel_launch(void* const* d_in, const int* in_sizes, int n_in,
                              void* d_out, int out_size, void* d_ws, size_t ws_size,
                              hipStream_t stream) {
  const float* x   = (const float*)d_in[0];
  const float* h0  = (const float*)d_in[1];
  const float* w1  = (const float*)d_in[2];
  const float* b1  = (const float*)d_in[3];
  const float* w2  = (const float*)d_in[4];
  const float* b2  = (const float*)d_in[5];
  const float* wih = (const float*)d_in[6];
  const float* whh = (const float*)d_in[7];
  const float* bih = (const float*)d_in[8];
  const float* bhh = (const float*)d_in[9];
  const float* fcw = (const float*)d_in[10];
  const float* fcb = (const float*)d_in[11];

  char* p = (char*)d_ws;
  u16*   y1    = (u16*)p;   p += 28213248ull;   // 256*84*41*16 bf16 (NHWC)
  u16*   yb    = (u16*)p;   p += 3211264ull;    // 32*8*6272 bf16
  float* gi    = (float*)p; p += 9633792ull;    // 256*9408 f32
  u16*   w2pk  = (u16*)p;   p += 8192ull;       // packed conv2 weights
  u16*   w1pk  = (u16*)p;   p += 8192ull;       // packed conv1 weights (5 frags)
  float* hf0   = (float*)p; p += 100352ull;     // 8*3136 f32
  float* hf1   = (float*)p; p += 100352ull;
  u16*   hb0   = (u16*)p;   p += 100352ull;     // 16*3136 bf16 (padded)
  u16*   hb1   = (u16*)p;   p += 100352ull;

  k_init_h<<<196, 256, 0, stream>>>(h0, hb0, hb1, hf0);
  k_pack_w1<<<10, 256, 0, stream>>>(w1, w1pk);
  k_pack_w2<<<16, 256, 0, stream>>>(w2, w2pk);
  k_conv1<<<dim3(21, 256), 256, 0, stream>>>(x, w1pk, b1, y1);
  k_conv2<<<dim3(7, 256), 256, 0, stream>>>(y1, w2pk, b2, yb);
  k_gemm_gi<<<147, 256, 0, stream>>>(yb, wih, bih, gi);

  void* args[] = { (void*)&whh, (void*)&gi, (void*)&bhh,
                   (void*)&hb0, (void*)&hb1, (void*)&hf0, (void*)&hf1 };
  hipLaunchCooperativeKernel((void*)k_gru_all, dim3(196), dim3(512),
                             args, 0, stream);

  k_fc<<<16, 64, 0, stream>>>(hf0, fcw, fcb, (float*)d_out);
}